// Round 5
// baseline (164.956 us; speedup 1.0000x reference)
//
#include <hip/hip_runtime.h>
#include <math.h>

#define NTOK   16384
#define DIM    2048
#define NEXP   64
#define TOPK   8
#define TB     32          // tokens per block
#define KC     64          // K chunk
#define NCHUNK (DIM / KC)  // 32
#define XP     65          // ODD stride (doubles): bankpair=(row+k)%16 -> conflict-free
#define PP     65

typedef double v4d __attribute__((ext_vector_type(4)));

// ---------------- kernel 1: per-expert inverse norms (f64) ----------------
__global__ __launch_bounds__(64) void proto_norm_kernel(
    const float* __restrict__ proto, double* __restrict__ pinv)
{
    const int e = blockIdx.x;
    const int lane = threadIdx.x;
    const float* row = proto + e * DIM;
    double s = 0.0;
#pragma unroll
    for (int i = 0; i < DIM / 64; ++i) {
        float v = row[lane + 64 * i];
        s += (double)v * (double)v;
    }
#pragma unroll
    for (int d = 1; d < 64; d <<= 1)
        s += __shfl_xor(s, d, 64);
    if (lane == 0)
        pinv[e] = 1.0 / fmax(sqrt(s), 1e-12);
}

// ---------------- kernel 2: f64-MFMA logits, conflict-free LDS, async stage ----------------
__global__ __launch_bounds__(256, 2) void router_kernel(
    const float* __restrict__ x, const float* __restrict__ proto,
    const double* __restrict__ pinv, float* __restrict__ out)
{
    __shared__ double p_lds[NEXP][PP];   // 33280 B, row-major [e][k]
    __shared__ double x_lds[TB][XP];     // 16640 B, row-major [t][k]
    __shared__ double xinv_lds[TB];
    __shared__ double pinv_lds[NEXP];
    float* logits = reinterpret_cast<float*>(&x_lds[0][0]);  // [TB][NEXP] f32, reused

    const int tid  = threadIdx.x;
    const int lane = tid & 63;
    const int w    = tid >> 6;               // wave 0..3
    const int tok0 = blockIdx.x * TB;

    // staging assignment
    const int sx_t = tid >> 3;               // token 0..31 (8 thr/token)
    const int sx_k = (tid & 7) * 8;          // 8 floats each
    const int sp_e = tid >> 2;               // expert 0..63 (4 thr/expert)
    const int sp_k = (tid & 3) * 16;         // 16 floats each

    // MFMA tile assignment: 2 t-tiles x 2 e-pairs, 1 (t,epair) per wave
    const int ttile = w & 1;
    const int epair = w >> 1;
    const int arow  = lane & 15;             // my A-row / B-col label
    const int akg   = lane >> 4;             // my k label (irrelevant to result)

    if (tid < NEXP) pinv_lds[tid] = pinv[tid];

    // ---- layout calibration: discover true (lane,reg) -> (row,col) mapping ----
    v4d c1 = {0.0, 0.0, 0.0, 0.0};
    v4d c2 = {0.0, 0.0, 0.0, 0.0};
    c1 = __builtin_amdgcn_mfma_f64_16x16x4f64((double)arow, 1.0, c1, 0, 0, 0);
    c2 = __builtin_amdgcn_mfma_f64_16x16x4f64(1.0, (double)arow, c2, 0, 0, 0);

    v4d acc0 = {0.0, 0.0, 0.0, 0.0};
    v4d acc1 = {0.0, 0.0, 0.0, 0.0};
    double sumsq = 0.0;

    const float* xsrc = x + (size_t)(tok0 + sx_t) * DIM + sx_k;
    const float* psrc = proto + (size_t)sp_e * DIM + sp_k;

    // ---- prologue: prefetch chunk 0 into registers ----
    float4 rx0 = *(const float4*)(xsrc);
    float4 rx1 = *(const float4*)(xsrc + 4);
    float4 rp0 = *(const float4*)(psrc);
    float4 rp1 = *(const float4*)(psrc + 4);
    float4 rp2 = *(const float4*)(psrc + 8);
    float4 rp3 = *(const float4*)(psrc + 12);

    for (int c = 0; c < NCHUNK; ++c) {
        __syncthreads();   // previous chunk's LDS reads complete
        // ---- write staged regs -> LDS (cvt f64), fuse token sumsq ----
        {
            double d0 = (double)rx0.x, d1 = (double)rx0.y,
                   d2 = (double)rx0.z, d3 = (double)rx0.w;
            double d4 = (double)rx1.x, d5 = (double)rx1.y,
                   d6 = (double)rx1.z, d7 = (double)rx1.w;
            double* xr = &x_lds[sx_t][sx_k];
            xr[0] = d0; xr[1] = d1; xr[2] = d2; xr[3] = d3;
            xr[4] = d4; xr[5] = d5; xr[6] = d6; xr[7] = d7;
            sumsq += d0 * d0 + d1 * d1 + d2 * d2 + d3 * d3 +
                     d4 * d4 + d5 * d5 + d6 * d6 + d7 * d7;
            double* pr = &p_lds[sp_e][sp_k];
            pr[0]  = (double)rp0.x; pr[1]  = (double)rp0.y;
            pr[2]  = (double)rp0.z; pr[3]  = (double)rp0.w;
            pr[4]  = (double)rp1.x; pr[5]  = (double)rp1.y;
            pr[6]  = (double)rp1.z; pr[7]  = (double)rp1.w;
            pr[8]  = (double)rp2.x; pr[9]  = (double)rp2.y;
            pr[10] = (double)rp2.z; pr[11] = (double)rp2.w;
            pr[12] = (double)rp3.x; pr[13] = (double)rp3.y;
            pr[14] = (double)rp3.z; pr[15] = (double)rp3.w;
        }
        __syncthreads();   // LDS ready
        // ---- async stage: issue next chunk's loads BEFORE compute ----
        if (c + 1 < NCHUNK) {
            const int off = (c + 1) * KC;
            rx0 = *(const float4*)(xsrc + off);
            rx1 = *(const float4*)(xsrc + off + 4);
            rp0 = *(const float4*)(psrc + off);
            rp1 = *(const float4*)(psrc + off + 4);
            rp2 = *(const float4*)(psrc + off + 8);
            rp3 = *(const float4*)(psrc + off + 12);
        }
        // ---- compute: 16 MFMA K-steps, 2 e-tiles per wave ----
#pragma unroll
        for (int ks = 0; ks < KC / 4; ++ks) {
            const int k = ks * 4 + akg;
            double a  = x_lds[ttile * 16 + arow][k];
            double b0 = p_lds[epair * 32 + arow][k];
            double b1 = p_lds[epair * 32 + 16 + arow][k];
            acc0 = __builtin_amdgcn_mfma_f64_16x16x4f64(a, b0, acc0, 0, 0, 0);
            acc1 = __builtin_amdgcn_mfma_f64_16x16x4f64(a, b1, acc1, 0, 0, 0);
        }
    }

    // ---- token inverse norms: reduce 8 consecutive threads per token ----
    {
        double s = sumsq;
#pragma unroll
        for (int d = 1; d < 8; d <<= 1)
            s += __shfl_down(s, d, 8);
        if ((tid & 7) == 0)
            xinv_lds[sx_t] = 1.0 / fmax(sqrt(s), 1e-12);
    }
    __syncthreads();   // also guards: all MFMA LDS reads done before logits alias-write

    // ---- scale to cosine logits using calibrated labels, cast fp32, reshard ----
#pragma unroll
    for (int i = 0; i < 4; ++i) {
        const int tr = (int)(c1[i] * 0.25);      // true token-within-tile label
        const int ec = (int)(c2[i] * 0.25);      // true expert-within-16 label
        const int tl = ttile * 16 + tr;
        const double xi = xinv_lds[tl];
        const int e0 = epair * 32 + ec;
        const int e1 = epair * 32 + 16 + ec;
        logits[tl * NEXP + e0] = (float)(acc0[i] * xi * pinv_lds[e0]);
        logits[tl * NEXP + e1] = (float)(acc1[i] * xi * pinv_lds[e1]);
    }
    __syncthreads();

    // ---- epilogue: np fp32 softmax bit-chain + rank by (w32 desc, idx asc) ----
#pragma unroll 1
    for (int i = 0; i < 8; ++i) {
        const int tl = w * 8 + i;
        const float l32 = logits[tl * NEXP + lane];

        float m = l32;
#pragma unroll
        for (int d = 1; d < 64; d <<= 1) {
            float o = __shfl_xor(m, d, 64);
            m = fmaxf(m, o);
        }
        const float dd = l32 - m;
        const float e32 = (float)exp((double)dd);

        // numpy pairwise_sum (n=64): 8 accumulators over stride 8
        float r[8];
#pragma unroll
        for (int j = 0; j < 8; ++j) {
            float rj = __shfl(e32, j, 64);
#pragma unroll
            for (int b = 1; b < 8; ++b)
                rj += __shfl(e32, j + 8 * b, 64);
            r[j] = rj;
        }
        const float S = ((r[0] + r[1]) + (r[2] + r[3])) +
                        ((r[4] + r[5]) + (r[6] + r[7]));
        const float wgt = e32 / S;

        int rank = 0;
#pragma unroll 1
        for (int sdist = 1; sdist < 64; ++sdist) {
            float ow = __shfl_xor(wgt, sdist, 64);
            int j = lane ^ sdist;
            rank += (ow > wgt) || (ow == wgt && j < lane);
        }

        if (rank < TOPK) {
            const int tok = tok0 + tl;
            out[tok * TOPK + rank] = wgt;                       // routing_weights
            out[NTOK * TOPK + tok * TOPK + rank] = (float)lane; // selected_experts
        }
    }
}

extern "C" void kernel_launch(void* const* d_in, const int* in_sizes, int n_in,
                              void* d_out, int out_size, void* d_ws, size_t ws_size,
                              hipStream_t stream) {
    const float* x     = (const float*)d_in[0];
    const float* proto = (const float*)d_in[1];
    float* out         = (float*)d_out;
    double* pinv       = (double*)d_ws;  // 64 doubles

    proto_norm_kernel<<<NEXP, 64, 0, stream>>>(proto, pinv);
    router_kernel<<<NTOK / TB, 256, 0, stream>>>(x, proto, pinv, out);
}

// Round 6
// 139.895 us; speedup vs baseline: 1.1791x; 1.1791x over previous
//
#include <hip/hip_runtime.h>
#include <math.h>

#define NTOK   16384
#define DIM    2048
#define NEXP   64
#define TOPK   8
#define TB     32          // tokens per block
#define KC     64          // K chunk
#define NCHUNK (DIM / KC)  // 32
#define XS     68          // f32 row stride: bank=(4*row+k)%32 -> conflict-free reads
#define PSR    68

typedef double v4d __attribute__((ext_vector_type(4)));

// ---- single fused kernel: f64-MFMA logits + norms + fp32 softmax + top-k ----
__global__ __launch_bounds__(256, 2) void router_kernel(
    const float* __restrict__ x, const float* __restrict__ proto,
    float* __restrict__ out)
{
    __shared__ float  p_lds[2][NEXP][PSR];  // 2 x 17408 B, [e][k] f32
    __shared__ float  x_lds[2][TB][XS];     // 2 x  8704 B, [t][k] f32
    __shared__ double xinv_lds[TB];
    __shared__ double pinv_lds[NEXP];
    float* logits = &x_lds[0][0][0];        // [TB][NEXP] f32, reused after loop

    const int tid  = threadIdx.x;
    const int lane = tid & 63;
    const int w    = tid >> 6;              // wave 0..3
    const int tok0 = blockIdx.x * TB;

    // staging assignment
    const int sx_t = tid >> 3;              // token 0..31 (8 thr/token)
    const int sx_k = (tid & 7) * 8;         // 8 floats each
    const int sp_e = tid >> 2;              // expert 0..63 (4 thr/expert)
    const int sp_k = (tid & 3) * 16;        // 16 floats each

    // MFMA tile assignment
    const int ttile = w & 1;
    const int epair = w >> 1;
    const int arow  = lane & 15;            // A-row / B-col label
    const int akg   = lane >> 4;            // k sub-label

    // ---- layout calibration (verified r4): (lane,reg) -> (row,col) ----
    v4d c1 = {0., 0., 0., 0.}, c2 = {0., 0., 0., 0.};
    c1 = __builtin_amdgcn_mfma_f64_16x16x4f64((double)arow, 1.0, c1, 0, 0, 0);
    c2 = __builtin_amdgcn_mfma_f64_16x16x4f64(1.0, (double)arow, c2, 0, 0, 0);

    v4d acc0 = {0., 0., 0., 0.}, acc1 = {0., 0., 0., 0.};
    double sumsq = 0.0, psumsq = 0.0;

    const float* xsrc = x + (size_t)(tok0 + sx_t) * DIM + sx_k;
    const float* psrc = proto + (size_t)sp_e * DIM + sp_k;

    float4 rx0, rx1, rp0, rp1, rp2, rp3;

    auto gload = [&](int c) {
        const int off = c * KC;
        rx0 = *(const float4*)(xsrc + off);
        rx1 = *(const float4*)(xsrc + off + 4);
        rp0 = *(const float4*)(psrc + off);
        rp1 = *(const float4*)(psrc + off + 4);
        rp2 = *(const float4*)(psrc + off + 8);
        rp3 = *(const float4*)(psrc + off + 12);
    };
    auto stage = [&](int b) {
        *(float4*)&x_lds[b][sx_t][sx_k]     = rx0;
        *(float4*)&x_lds[b][sx_t][sx_k + 4] = rx1;
        sumsq += (double)rx0.x * rx0.x + (double)rx0.y * rx0.y
               + (double)rx0.z * rx0.z + (double)rx0.w * rx0.w
               + (double)rx1.x * rx1.x + (double)rx1.y * rx1.y
               + (double)rx1.z * rx1.z + (double)rx1.w * rx1.w;
        *(float4*)&p_lds[b][sp_e][sp_k]      = rp0;
        *(float4*)&p_lds[b][sp_e][sp_k + 4]  = rp1;
        *(float4*)&p_lds[b][sp_e][sp_k + 8]  = rp2;
        *(float4*)&p_lds[b][sp_e][sp_k + 12] = rp3;
        psumsq += (double)rp0.x * rp0.x + (double)rp0.y * rp0.y
                + (double)rp0.z * rp0.z + (double)rp0.w * rp0.w
                + (double)rp1.x * rp1.x + (double)rp1.y * rp1.y
                + (double)rp1.z * rp1.z + (double)rp1.w * rp1.w
                + (double)rp2.x * rp2.x + (double)rp2.y * rp2.y
                + (double)rp2.z * rp2.z + (double)rp2.w * rp2.w
                + (double)rp3.x * rp3.x + (double)rp3.y * rp3.y
                + (double)rp3.z * rp3.z + (double)rp3.w * rp3.w;
    };

    // ---- prologue: chunk 0 staged, chunk 1 in registers ----
    gload(0);
    stage(0);
    gload(1);
    __syncthreads();

    // ---- main loop: 1 barrier/chunk, stage(c+1) overlaps compute(c) ----
    for (int c = 0; c < NCHUNK; ++c) {
        const int cur = c & 1;
        if (c + 1 < NCHUNK) {
            stage(cur ^ 1);                  // regs (chunk c+1) -> LDS buf nxt
            if (c + 2 < NCHUNK) gload(c + 2); // issue HBM loads 2 chunks ahead
        }
        const float* xr  = &x_lds[cur][ttile * 16 + arow][akg];
        const float* b0r = &p_lds[cur][epair * 32 + arow][akg];
        const float* b1r = &p_lds[cur][epair * 32 + 16 + arow][akg];
        float fa = xr[0], f0 = b0r[0], f1 = b1r[0];
#pragma unroll
        for (int ks = 0; ks < KC / 4; ++ks) {
            float na = 0.f, n0 = 0.f, n1 = 0.f;
            if (ks < KC / 4 - 1) {           // prefetch ks+1 before ks's MFMAs
                na = xr[(ks + 1) * 4];
                n0 = b0r[(ks + 1) * 4];
                n1 = b1r[(ks + 1) * 4];
            }
            acc0 = __builtin_amdgcn_mfma_f64_16x16x4f64((double)fa, (double)f0, acc0, 0, 0, 0);
            acc1 = __builtin_amdgcn_mfma_f64_16x16x4f64((double)fa, (double)f1, acc1, 0, 0, 0);
            fa = na; f0 = n0; f1 = n1;
        }
        __syncthreads();
    }

    // ---- token inverse norms: reduce 8 consecutive threads per token ----
    {
        double s = sumsq;
#pragma unroll
        for (int d = 1; d < 8; d <<= 1)
            s += __shfl_down(s, d, 8);
        if ((tid & 7) == 0)
            xinv_lds[sx_t] = 1.0 / fmax(sqrt(s), 1e-12);
    }
    // ---- expert inverse norms: reduce 4 consecutive threads per expert ----
    {
        double s = psumsq;
        s += __shfl_down(s, 1, 4);
        s += __shfl_down(s, 2, 4);
        if ((tid & 3) == 0)
            pinv_lds[sp_e] = 1.0 / fmax(sqrt(s), 1e-12);
    }
    __syncthreads();

    // ---- scale to cosine logits via calibrated labels, cast fp32, reshard ----
#pragma unroll
    for (int i = 0; i < 4; ++i) {
        const int tr = (int)(c1[i] * 0.25);     // true token-within-tile label
        const int ec = (int)(c2[i] * 0.25);     // true expert-within-16 label
        const int tl = ttile * 16 + tr;
        const double xi = xinv_lds[tl];
        const int e0 = epair * 32 + ec;
        const int e1 = epair * 32 + 16 + ec;
        logits[tl * NEXP + e0] = (float)(acc0[i] * xi * pinv_lds[e0]);
        logits[tl * NEXP + e1] = (float)(acc1[i] * xi * pinv_lds[e1]);
    }
    __syncthreads();

    // ---- epilogue: np fp32 softmax bit-chain + rank by (w32 desc, idx asc) ----
#pragma unroll 1
    for (int i = 0; i < 8; ++i) {
        const int tl = w * 8 + i;
        const float l32 = logits[tl * NEXP + lane];

        float m = l32;
#pragma unroll
        for (int d = 1; d < 64; d <<= 1) {
            float o = __shfl_xor(m, d, 64);
            m = fmaxf(m, o);
        }
        const float dd = l32 - m;
        const float e32 = (float)exp((double)dd);

        // numpy pairwise_sum (n=64): 8 accumulators over stride 8
        float r[8];
#pragma unroll
        for (int j = 0; j < 8; ++j) {
            float rj = __shfl(e32, j, 64);
#pragma unroll
            for (int b = 1; b < 8; ++b)
                rj += __shfl(e32, j + 8 * b, 64);
            r[j] = rj;
        }
        const float S = ((r[0] + r[1]) + (r[2] + r[3])) +
                        ((r[4] + r[5]) + (r[6] + r[7]));
        const float wgt = e32 / S;

        int rank = 0;
#pragma unroll 1
        for (int sdist = 1; sdist < 64; ++sdist) {
            float ow = __shfl_xor(wgt, sdist, 64);
            int j = lane ^ sdist;
            rank += (ow > wgt) || (ow == wgt && j < lane);
        }

        if (rank < TOPK) {
            const int tok = tok0 + tl;
            out[tok * TOPK + rank] = wgt;                       // routing_weights
            out[NTOK * TOPK + tok * TOPK + rank] = (float)lane; // selected_experts
        }
    }
}

extern "C" void kernel_launch(void* const* d_in, const int* in_sizes, int n_in,
                              void* d_out, int out_size, void* d_ws, size_t ws_size,
                              hipStream_t stream) {
    const float* x     = (const float*)d_in[0];
    const float* proto = (const float*)d_in[1];
    float* out         = (float*)d_out;
    (void)d_ws; (void)ws_size; (void)in_sizes; (void)n_in; (void)out_size;

    router_kernel<<<NTOK / TB, 256, 0, stream>>>(x, proto, out);
}

// Round 7
// 139.035 us; speedup vs baseline: 1.1864x; 1.0062x over previous
//
#include <hip/hip_runtime.h>
#include <math.h>

#define NTOK   16384
#define DIM    2048
#define NEXP   64
#define TOPK   8
#define TB     32          // tokens per block
#define KC     64          // K chunk
#define NCHUNK (DIM / KC)  // 32
#define XS     68          // f32 row stride: all LDS phases <=2-deep on bank quads
#define PSR    68

typedef double v4d __attribute__((ext_vector_type(4)));

// ---- single fused kernel: f64-MFMA logits + norms + fp32 softmax + top-k ----
__global__ __launch_bounds__(256, 2) void router_kernel(
    const float* __restrict__ x, const float* __restrict__ proto,
    float* __restrict__ out)
{
    __shared__ float  p_lds[2][NEXP][PSR];  // 2 x 17408 B, [e][k] f32
    __shared__ float  x_lds[2][TB][XS];     // 2 x  8704 B, [t][k] f32
    __shared__ double xinv_lds[TB];
    __shared__ double pinv_lds[NEXP];
    float* logits = &x_lds[0][0][0];        // [TB][NEXP] f32, reused after loop

    const int tid  = threadIdx.x;
    const int lane = tid & 63;
    const int w    = tid >> 6;              // wave 0..3
    const int tok0 = blockIdx.x * TB;

    // staging assignment
    const int sx_t = tid >> 3;              // token 0..31 (8 thr/token)
    const int sx_k = (tid & 7) * 8;         // 8 floats each
    const int sp_e = tid >> 2;              // expert 0..63 (4 thr/expert)
    const int sp_k = (tid & 3) * 16;        // 16 floats each

    // MFMA tile assignment
    const int ttile = w & 1;
    const int epair = w >> 1;
    const int arow  = lane & 15;            // A-row / B-col label
    const int akg   = lane >> 4;            // quarter-wave k-group
    const int kbase = akg * 16;             // this lane's private 16-k segment

    // ---- layout calibration (verified r4): (lane,reg) -> (row,col) ----
    v4d c1 = {0., 0., 0., 0.}, c2 = {0., 0., 0., 0.};
    c1 = __builtin_amdgcn_mfma_f64_16x16x4f64((double)arow, 1.0, c1, 0, 0, 0);
    c2 = __builtin_amdgcn_mfma_f64_16x16x4f64(1.0, (double)arow, c2, 0, 0, 0);

    v4d acc0 = {0., 0., 0., 0.}, acc1 = {0., 0., 0., 0.};
    double sumsq = 0.0, psumsq = 0.0;

    const float* xsrc = x + (size_t)(tok0 + sx_t) * DIM + sx_k;
    const float* psrc = proto + (size_t)sp_e * DIM + sp_k;

    float4 rx0, rx1, rp0, rp1, rp2, rp3;

    auto gload = [&](int c) {
        const int off = c * KC;
        rx0 = *(const float4*)(xsrc + off);
        rx1 = *(const float4*)(xsrc + off + 4);
        rp0 = *(const float4*)(psrc + off);
        rp1 = *(const float4*)(psrc + off + 4);
        rp2 = *(const float4*)(psrc + off + 8);
        rp3 = *(const float4*)(psrc + off + 12);
    };
    auto stage = [&](int b) {
        *(float4*)&x_lds[b][sx_t][sx_k]     = rx0;
        *(float4*)&x_lds[b][sx_t][sx_k + 4] = rx1;
        sumsq += (double)rx0.x * rx0.x + (double)rx0.y * rx0.y
               + (double)rx0.z * rx0.z + (double)rx0.w * rx0.w
               + (double)rx1.x * rx1.x + (double)rx1.y * rx1.y
               + (double)rx1.z * rx1.z + (double)rx1.w * rx1.w;
        *(float4*)&p_lds[b][sp_e][sp_k]      = rp0;
        *(float4*)&p_lds[b][sp_e][sp_k + 4]  = rp1;
        *(float4*)&p_lds[b][sp_e][sp_k + 8]  = rp2;
        *(float4*)&p_lds[b][sp_e][sp_k + 12] = rp3;
        psumsq += (double)rp0.x * rp0.x + (double)rp0.y * rp0.y
                + (double)rp0.z * rp0.z + (double)rp0.w * rp0.w
                + (double)rp1.x * rp1.x + (double)rp1.y * rp1.y
                + (double)rp1.z * rp1.z + (double)rp1.w * rp1.w
                + (double)rp2.x * rp2.x + (double)rp2.y * rp2.y
                + (double)rp2.z * rp2.z + (double)rp2.w * rp2.w
                + (double)rp3.x * rp3.x + (double)rp3.y * rp3.y
                + (double)rp3.z * rp3.z + (double)rp3.w * rp3.w;
    };

    // ---- prologue: chunk 0 staged, chunk 1 in registers ----
    gload(0);
    stage(0);
    gload(1);
    __syncthreads();

    const int xrow  = ttile * 16 + arow;
    const int b0row = epair * 32 + arow;
    const int b1row = epair * 32 + 16 + arow;

    // ---- main loop: 1 barrier/chunk; chunk operands bulk-loaded b128 ----
    for (int c = 0; c < NCHUNK; ++c) {
        const int cur = c & 1;

        // bulk-load this chunk's MFMA operands: 12x ds_read_b128, issued up front.
        // k-slot freedom: quarter-wave akg supplies k = kbase + (4q+s); a/b lanes
        // of the same quarter read the same k -> dot values bit-identical (r4).
        float4 ax[4], bx0[4], bx1[4];
#pragma unroll
        for (int q = 0; q < 4; ++q) {
            ax[q]  = *(const float4*)&x_lds[cur][xrow][kbase + 4 * q];
            bx0[q] = *(const float4*)&p_lds[cur][b0row][kbase + 4 * q];
            bx1[q] = *(const float4*)&p_lds[cur][b1row][kbase + 4 * q];
        }

        // stage next chunk (regs -> LDS other buffer), then issue HBM loads c+2
        if (c + 1 < NCHUNK) {
            stage(cur ^ 1);
            if (c + 2 < NCHUNK) gload(c + 2);
        }

        // 32 MFMAs, no LDS on the critical path
#pragma unroll
        for (int q = 0; q < 4; ++q) {
            acc0 = __builtin_amdgcn_mfma_f64_16x16x4f64((double)ax[q].x, (double)bx0[q].x, acc0, 0, 0, 0);
            acc1 = __builtin_amdgcn_mfma_f64_16x16x4f64((double)ax[q].x, (double)bx1[q].x, acc1, 0, 0, 0);
            acc0 = __builtin_amdgcn_mfma_f64_16x16x4f64((double)ax[q].y, (double)bx0[q].y, acc0, 0, 0, 0);
            acc1 = __builtin_amdgcn_mfma_f64_16x16x4f64((double)ax[q].y, (double)bx1[q].y, acc1, 0, 0, 0);
            acc0 = __builtin_amdgcn_mfma_f64_16x16x4f64((double)ax[q].z, (double)bx0[q].z, acc0, 0, 0, 0);
            acc1 = __builtin_amdgcn_mfma_f64_16x16x4f64((double)ax[q].z, (double)bx1[q].z, acc1, 0, 0, 0);
            acc0 = __builtin_amdgcn_mfma_f64_16x16x4f64((double)ax[q].w, (double)bx0[q].w, acc0, 0, 0, 0);
            acc1 = __builtin_amdgcn_mfma_f64_16x16x4f64((double)ax[q].w, (double)bx1[q].w, acc1, 0, 0, 0);
        }
        __syncthreads();
    }

    // ---- token inverse norms: reduce 8 consecutive threads per token ----
    {
        double s = sumsq;
#pragma unroll
        for (int d = 1; d < 8; d <<= 1)
            s += __shfl_down(s, d, 8);
        if ((tid & 7) == 0)
            xinv_lds[sx_t] = 1.0 / fmax(sqrt(s), 1e-12);
    }
    // ---- expert inverse norms: reduce 4 consecutive threads per expert ----
    {
        double s = psumsq;
        s += __shfl_down(s, 1, 4);
        s += __shfl_down(s, 2, 4);
        if ((tid & 3) == 0)
            pinv_lds[sp_e] = 1.0 / fmax(sqrt(s), 1e-12);
    }
    __syncthreads();

    // ---- scale to cosine logits via calibrated labels, cast fp32, reshard ----
#pragma unroll
    for (int i = 0; i < 4; ++i) {
        const int tr = (int)(c1[i] * 0.25);     // true token-within-tile label
        const int ec = (int)(c2[i] * 0.25);     // true expert-within-16 label
        const int tl = ttile * 16 + tr;
        const double xi = xinv_lds[tl];
        const int e0 = epair * 32 + ec;
        const int e1 = epair * 32 + 16 + ec;
        logits[tl * NEXP + e0] = (float)(acc0[i] * xi * pinv_lds[e0]);
        logits[tl * NEXP + e1] = (float)(acc1[i] * xi * pinv_lds[e1]);
    }
    __syncthreads();

    // ---- epilogue: np fp32 softmax bit-chain + rank by (w32 desc, idx asc) ----
#pragma unroll 1
    for (int i = 0; i < 8; ++i) {
        const int tl = w * 8 + i;
        const float l32 = logits[tl * NEXP + lane];

        float m = l32;
#pragma unroll
        for (int d = 1; d < 64; d <<= 1) {
            float o = __shfl_xor(m, d, 64);
            m = fmaxf(m, o);
        }
        const float dd = l32 - m;
        const float e32 = (float)exp((double)dd);

        // numpy pairwise_sum (n=64): 8 accumulators over stride 8
        float r[8];
#pragma unroll
        for (int j = 0; j < 8; ++j) {
            float rj = __shfl(e32, j, 64);
#pragma unroll
            for (int b = 1; b < 8; ++b)
                rj += __shfl(e32, j + 8 * b, 64);
            r[j] = rj;
        }
        const float S = ((r[0] + r[1]) + (r[2] + r[3])) +
                        ((r[4] + r[5]) + (r[6] + r[7]));
        const float wgt = e32 / S;

        int rank = 0;
#pragma unroll 1
        for (int sdist = 1; sdist < 64; ++sdist) {
            float ow = __shfl_xor(wgt, sdist, 64);
            int j = lane ^ sdist;
            rank += (ow > wgt) || (ow == wgt && j < lane);
        }

        if (rank < TOPK) {
            const int tok = tok0 + tl;
            out[tok * TOPK + rank] = wgt;                       // routing_weights
            out[NTOK * TOPK + tok * TOPK + rank] = (float)lane; // selected_experts
        }
    }
}

extern "C" void kernel_launch(void* const* d_in, const int* in_sizes, int n_in,
                              void* d_out, int out_size, void* d_ws, size_t ws_size,
                              hipStream_t stream) {
    const float* x     = (const float*)d_in[0];
    const float* proto = (const float*)d_in[1];
    float* out         = (float*)d_out;
    (void)d_ws; (void)ws_size; (void)in_sizes; (void)n_in; (void)out_size;

    router_kernel<<<NTOK / TB, 256, 0, stream>>>(x, proto, out);
}